// Round 1
// baseline (1299.720 us; speedup 1.0000x reference)
//
#include <hip/hip_runtime.h>
#include <hip/hip_bf16.h>

// GraphSAGE 2-layer forward, fp32.
// Strategy: project-then-aggregate (mean(x[src])@W^T == segsum((x@W^T)[src])/cnt),
// which halves edge traffic for layer 2 (64-dim instead of 128-dim).
// Aggregation via global float atomics (round-1 baseline; CSR planned if atomics bound).

#define THREADS 256

// ---------------------------------------------------------------------------
// Edge-degree histogram: cnt[dst] += 1
__global__ __launch_bounds__(THREADS)
void sage_count(const int* __restrict__ dst, float* __restrict__ cnt, int E) {
    int i = blockIdx.x * THREADS + threadIdx.x;
    if (i < E) atomicAdd(&cnt[dst[i]], 1.0f);
}

// ---------------------------------------------------------------------------
// Scatter-add: agg[dst[e]*DIM + c] += p[src[e]*DIM + c]
// Thread-per-element mapping: consecutive lanes cover consecutive c of one edge
// -> coalesced 256B gathers, broadcast index loads via L1.
template<int DIM>
__global__ __launch_bounds__(THREADS)
void sage_scatter(const float* __restrict__ p, const int* __restrict__ src,
                  const int* __restrict__ dst, float* __restrict__ agg, int E) {
    const long long total = (long long)E * DIM;
    const long long stride = (long long)gridDim.x * THREADS;
    for (long long t = (long long)blockIdx.x * THREADS + threadIdx.x; t < total; t += stride) {
        int e = (int)(t / DIM);          // DIM is power of two -> shift
        int c = (int)(t & (DIM - 1));
        int s = src[e];
        int d = dst[e];
        atomicAdd(&agg[(size_t)d * DIM + c], p[(size_t)s * DIM + c]);
    }
}

// ---------------------------------------------------------------------------
// Fused GEMM: out[n][c] = optrelu( X[n,:]@W[c,:] + bias[c] + agg[n][c]/max(cnt[n],1) )
// X: [N,128] (K=128 fixed), W: [DOUT,128] row-major, out: [N,DOUT].
// Block tile: 32 rows x 64 cols; blockIdx.y selects 64-col slab (DOUT=128 -> 2 slabs).
// W staged transposed in LDS ws[k][col] (pad+4), X tile in LDS xs[row][k] (pad+4).
// Per-thread: 2 rows x 4 cols, k unrolled by 4, all LDS reads are b128.
template<int DOUT>
__global__ __launch_bounds__(THREADS)
void sage_gemm(const float* __restrict__ X, const float* __restrict__ W,
               const float* __restrict__ bias, const float* __restrict__ agg,
               const float* __restrict__ cnt, float* __restrict__ out,
               int N, int doRelu) {
    constexpr int COLS = 64;           // col-slab per block
    constexpr int ROWS = 32;           // rows per block
    __shared__ float ws[128][COLS + 4];
    __shared__ float xs[ROWS][128 + 4];

    const int tid = threadIdx.x;
    const int r0 = blockIdx.x * ROWS;
    const int colbase = blockIdx.y * COLS;

    // Stage W slab transposed: ws[k][col] = W[colbase+col][k]
    for (int i = tid; i < COLS * 128; i += THREADS) {
        int col = i >> 7, k = i & 127;
        ws[k][col] = W[(size_t)(colbase + col) * 128 + k];
    }
    // Stage X tile (float4 coalesced)
    for (int i = tid; i < ROWS * 32; i += THREADS) {
        int row = i >> 5, kq = i & 31;
        int n = r0 + row;
        float4 v = make_float4(0.f, 0.f, 0.f, 0.f);
        if (n < N) v = *(const float4*)&X[(size_t)n * 128 + kq * 4];
        *(float4*)&xs[row][kq * 4] = v;
    }
    __syncthreads();

    const int c0 = (tid & 15) * 4;       // col within slab
    const int rb = (tid >> 4) * 2;       // row pair
    float acc[2][4] = {{0.f,0.f,0.f,0.f},{0.f,0.f,0.f,0.f}};

    for (int k = 0; k < 128; k += 4) {
        float4 x0 = *(const float4*)&xs[rb][k];
        float4 x1 = *(const float4*)&xs[rb + 1][k];
        #pragma unroll
        for (int i = 0; i < 4; ++i) {
            float4 w4 = *(const float4*)&ws[k + i][c0];
            float xv0 = (&x0.x)[i];
            float xv1 = (&x1.x)[i];
            acc[0][0] += xv0 * w4.x; acc[0][1] += xv0 * w4.y;
            acc[0][2] += xv0 * w4.z; acc[0][3] += xv0 * w4.w;
            acc[1][0] += xv1 * w4.x; acc[1][1] += xv1 * w4.y;
            acc[1][2] += xv1 * w4.z; acc[1][3] += xv1 * w4.w;
        }
    }

    #pragma unroll
    for (int r = 0; r < 2; ++r) {
        int n = r0 + rb + r;
        if (n >= N) continue;
        int c = colbase + c0;
        float4 o = make_float4(acc[r][0], acc[r][1], acc[r][2], acc[r][3]);
        if (bias) {
            o.x += bias[c];     o.y += bias[c + 1];
            o.z += bias[c + 2]; o.w += bias[c + 3];
        }
        if (agg) {
            float rc = 1.0f / fmaxf(cnt[n], 1.0f);
            float4 a = *(const float4*)&agg[(size_t)n * DOUT + c];
            o.x += a.x * rc; o.y += a.y * rc; o.z += a.z * rc; o.w += a.w * rc;
        }
        if (doRelu) {
            o.x = fmaxf(o.x, 0.f); o.y = fmaxf(o.y, 0.f);
            o.z = fmaxf(o.z, 0.f); o.w = fmaxf(o.w, 0.f);
        }
        *(float4*)&out[(size_t)n * DOUT + c] = o;
    }
}

// ---------------------------------------------------------------------------
extern "C" void kernel_launch(void* const* d_in, const int* in_sizes, int n_in,
                              void* d_out, int out_size, void* d_ws, size_t ws_size,
                              hipStream_t stream) {
    const float* x   = (const float*)d_in[0];
    const int* edges = (const int*)d_in[1];
    const float* Wl1 = (const float*)d_in[2];
    const float* Wr1 = (const float*)d_in[3];
    const float* b1  = (const float*)d_in[4];
    const float* Wl2 = (const float*)d_in[5];
    const float* Wr2 = (const float*)d_in[6];
    const float* b2  = (const float*)d_in[7];
    float* out = (float*)d_out;

    const int N = in_sizes[0] / 128;     // 50000
    const int E = in_sizes[1] / 2;       // 1600000
    const int* src = edges;              // edge_index[0]
    const int* dstv = edges + E;         // edge_index[1]

    // Workspace layout (floats): p1[N*128] | agg1[N*128] | h[N*128] | p2[N*64] | cnt[N]
    float* wsf  = (float*)d_ws;
    float* p1   = wsf;
    float* agg1 = p1 + (size_t)N * 128;
    float* h    = agg1 + (size_t)N * 128;
    float* p2   = h + (size_t)N * 128;
    float* cnt  = p2 + (size_t)N * 64;
    // total ~89.8 MB of d_ws

    hipMemsetAsync(agg1, 0, (size_t)N * 128 * sizeof(float), stream);
    hipMemsetAsync(cnt,  0, (size_t)N * sizeof(float), stream);
    hipMemsetAsync(out,  0, (size_t)N * 64 * sizeof(float), stream);   // agg2 accumulates here

    // degree
    sage_count<<<(E + THREADS - 1) / THREADS, THREADS, 0, stream>>>(dstv, cnt, E);

    dim3 g128((N + 31) / 32, 2);
    dim3 g64((N + 31) / 32, 1);

    // layer 1
    sage_gemm<128><<<g128, THREADS, 0, stream>>>(x, Wl1, nullptr, nullptr, nullptr, p1, N, 0);
    sage_scatter<128><<<8192, THREADS, 0, stream>>>(p1, src, dstv, agg1, E);
    sage_gemm<128><<<g128, THREADS, 0, stream>>>(x, Wr1, b1, agg1, cnt, h, N, 1);

    // layer 2
    sage_gemm<64><<<g64, THREADS, 0, stream>>>(h, Wl2, nullptr, nullptr, nullptr, p2, N, 0);
    sage_scatter<64><<<8192, THREADS, 0, stream>>>(p2, src, dstv, out, E);
    sage_gemm<64><<<g64, THREADS, 0, stream>>>(h, Wr2, b2, out, cnt, out, N, 0);
}

// Round 2
// 546.455 us; speedup vs baseline: 2.3785x; 2.3785x over previous
//
#include <hip/hip_runtime.h>
#include <hip/hip_bf16.h>

// GraphSAGE 2-layer forward, fp32.
// R2: replace float-atomic scatter (819 MB atomic write-through, 663us) with
// CSR gather-reduce: build CSR per call (hist + scan + fill, int atomics only),
// then one 32-lane group per dst node sums neighbor rows in registers.
// Project-then-aggregate keeps layer-2 edge traffic at 64 dims.

#define THREADS 256

// ---------------------------------------------------------------------------
// CSR build step 1: degree histogram (int)
__global__ __launch_bounds__(THREADS)
void hist_k(const int* __restrict__ dst, int* __restrict__ hist, int E) {
    int e = blockIdx.x * THREADS + threadIdx.x;
    if (e < E) atomicAdd(&hist[dst[e]], 1);
}

// CSR build step 2a: per-block inclusive scan (256 elems/block) + block sums
__global__ __launch_bounds__(THREADS)
void scan_block(const int* __restrict__ in, int* __restrict__ tmp,
                int* __restrict__ bsums, int n) {
    __shared__ int s[THREADS];
    int i = blockIdx.x * THREADS + threadIdx.x;
    int v = (i < n) ? in[i] : 0;
    s[threadIdx.x] = v;
    __syncthreads();
    for (int off = 1; off < THREADS; off <<= 1) {
        int t = (threadIdx.x >= off) ? s[threadIdx.x - off] : 0;
        __syncthreads();
        s[threadIdx.x] += t;
        __syncthreads();
    }
    if (i < n) tmp[i] = s[threadIdx.x];
    if (threadIdx.x == THREADS - 1) bsums[blockIdx.x] = s[threadIdx.x];
}

// CSR build step 2b: exclusive scan of block sums (single block, nb <= 256)
__global__ __launch_bounds__(THREADS)
void scan_bsums(int* __restrict__ bsums, int nb) {
    __shared__ int s[THREADS];
    int v = (threadIdx.x < nb) ? bsums[threadIdx.x] : 0;
    s[threadIdx.x] = v;
    __syncthreads();
    for (int off = 1; off < THREADS; off <<= 1) {
        int t = (threadIdx.x >= off) ? s[threadIdx.x - off] : 0;
        __syncthreads();
        s[threadIdx.x] += t;
        __syncthreads();
    }
    int excl = (threadIdx.x == 0) ? 0 : s[threadIdx.x - 1];
    if (threadIdx.x < nb) bsums[threadIdx.x] = excl;
}

// CSR build step 2c: rowptr[i] = exclusive_scan(hist)[i]; rowptr[n] = E
__global__ __launch_bounds__(THREADS)
void scan_finish(const int* __restrict__ tmp, const int* __restrict__ hist,
                 const int* __restrict__ bsums, int* __restrict__ rowptr,
                 int n, int E) {
    int i = blockIdx.x * THREADS + threadIdx.x;
    if (i < n) rowptr[i] = tmp[i] - hist[i] + bsums[i / THREADS];
    if (i == n) rowptr[n] = E;
}

// CSR build step 3: bucket-fill src ids grouped by dst
__global__ __launch_bounds__(THREADS)
void csr_fill(const int* __restrict__ src, const int* __restrict__ dst,
              const int* __restrict__ rowptr, int* __restrict__ fill,
              int* __restrict__ csr_src, int E) {
    int e = blockIdx.x * THREADS + threadIdx.x;
    if (e < E) {
        int d = dst[e];
        int pos = atomicAdd(&fill[d], 1);
        csr_src[rowptr[d] + pos] = src[e];
    }
}

// ---------------------------------------------------------------------------
// Gather-reduce: agg[n][:] = sum over neighbors s of p[s][:]
// LANES lanes per node (LANES*4 == DIM), float4 per lane. Neighbor ids are
// batch-loaded lane-parallel then broadcast with __shfl(width=LANES).
template<int DIM, int LANES>
__global__ __launch_bounds__(THREADS)
void sage_gather(const float* __restrict__ p, const int* __restrict__ rowptr,
                 const int* __restrict__ csr_src, float* __restrict__ agg, int N) {
    constexpr int GPER = THREADS / LANES;
    int g = blockIdx.x * GPER + threadIdx.x / LANES;
    if (g >= N) return;
    int lane = threadIdx.x % LANES;
    int start = rowptr[g], end = rowptr[g + 1];
    float4 acc = make_float4(0.f, 0.f, 0.f, 0.f);
    for (int base = start; base < end; base += LANES) {
        int my = base + lane;
        int sv = (my < end) ? csr_src[my] : 0;
        int m = min(LANES, end - base);
        #pragma unroll 4
        for (int j = 0; j < m; ++j) {
            int s = __shfl(sv, j, LANES);
            float4 v = *(const float4*)&p[(size_t)s * DIM + lane * 4];
            acc.x += v.x; acc.y += v.y; acc.z += v.z; acc.w += v.w;
        }
    }
    *(float4*)&agg[(size_t)g * DIM + lane * 4] = acc;
}

// ---------------------------------------------------------------------------
// Fused GEMM: out[n][c] = optrelu( X[n,:]@W[c,:] + bias[c] + agg[n][c]/max(deg[n],1) )
// deg[n] = rowptr[n+1] - rowptr[n]. Block tile 32 rows x 64 cols.
template<int DOUT>
__global__ __launch_bounds__(THREADS)
void sage_gemm(const float* __restrict__ X, const float* __restrict__ W,
               const float* __restrict__ bias, const float* __restrict__ agg,
               const int* __restrict__ rowptr, float* __restrict__ out,
               int N, int doRelu) {
    constexpr int COLS = 64;
    constexpr int ROWS = 32;
    __shared__ float ws[128][COLS + 4];
    __shared__ float xs[ROWS][128 + 4];

    const int tid = threadIdx.x;
    const int r0 = blockIdx.x * ROWS;
    const int colbase = blockIdx.y * COLS;

    for (int i = tid; i < COLS * 128; i += THREADS) {
        int col = i >> 7, k = i & 127;
        ws[k][col] = W[(size_t)(colbase + col) * 128 + k];
    }
    for (int i = tid; i < ROWS * 32; i += THREADS) {
        int row = i >> 5, kq = i & 31;
        int n = r0 + row;
        float4 v = make_float4(0.f, 0.f, 0.f, 0.f);
        if (n < N) v = *(const float4*)&X[(size_t)n * 128 + kq * 4];
        *(float4*)&xs[row][kq * 4] = v;
    }
    __syncthreads();

    const int c0 = (tid & 15) * 4;
    const int rb = (tid >> 4) * 2;
    float acc[2][4] = {{0.f,0.f,0.f,0.f},{0.f,0.f,0.f,0.f}};

    for (int k = 0; k < 128; k += 4) {
        float4 x0 = *(const float4*)&xs[rb][k];
        float4 x1 = *(const float4*)&xs[rb + 1][k];
        #pragma unroll
        for (int i = 0; i < 4; ++i) {
            float4 w4 = *(const float4*)&ws[k + i][c0];
            float xv0 = (&x0.x)[i];
            float xv1 = (&x1.x)[i];
            acc[0][0] += xv0 * w4.x; acc[0][1] += xv0 * w4.y;
            acc[0][2] += xv0 * w4.z; acc[0][3] += xv0 * w4.w;
            acc[1][0] += xv1 * w4.x; acc[1][1] += xv1 * w4.y;
            acc[1][2] += xv1 * w4.z; acc[1][3] += xv1 * w4.w;
        }
    }

    #pragma unroll
    for (int r = 0; r < 2; ++r) {
        int n = r0 + rb + r;
        if (n >= N) continue;
        int c = colbase + c0;
        float4 o = make_float4(acc[r][0], acc[r][1], acc[r][2], acc[r][3]);
        if (bias) {
            o.x += bias[c];     o.y += bias[c + 1];
            o.z += bias[c + 2]; o.w += bias[c + 3];
        }
        if (agg) {
            int deg = rowptr[n + 1] - rowptr[n];
            float rc = 1.0f / fmaxf((float)deg, 1.0f);
            float4 a = *(const float4*)&agg[(size_t)n * DOUT + c];
            o.x += a.x * rc; o.y += a.y * rc; o.z += a.z * rc; o.w += a.w * rc;
        }
        if (doRelu) {
            o.x = fmaxf(o.x, 0.f); o.y = fmaxf(o.y, 0.f);
            o.z = fmaxf(o.z, 0.f); o.w = fmaxf(o.w, 0.f);
        }
        *(float4*)&out[(size_t)n * DOUT + c] = o;
    }
}

// ---------------------------------------------------------------------------
extern "C" void kernel_launch(void* const* d_in, const int* in_sizes, int n_in,
                              void* d_out, int out_size, void* d_ws, size_t ws_size,
                              hipStream_t stream) {
    const float* x   = (const float*)d_in[0];
    const int* edges = (const int*)d_in[1];
    const float* Wl1 = (const float*)d_in[2];
    const float* Wr1 = (const float*)d_in[3];
    const float* b1  = (const float*)d_in[4];
    const float* Wl2 = (const float*)d_in[5];
    const float* Wr2 = (const float*)d_in[6];
    const float* b2  = (const float*)d_in[7];
    float* out = (float*)d_out;

    const int N = in_sizes[0] / 128;     // 50000
    const int E = in_sizes[1] / 2;       // 1600000
    const int* src = edges;
    const int* dstv = edges + E;

    // Workspace (floats / ints). Buffer reuse:
    //   A: p1 then h (p1 dead once agg1 is built)
    //   B: agg1 then p2 (agg1 dead once h is built)
    float* wsf = (float*)d_ws;
    float* A = wsf;                              // N*128
    float* B = A + (size_t)N * 128;              // N*128
    int* rowptr  = (int*)(B + (size_t)N * 128);  // N+1
    int* csr_src = rowptr + (N + 1);             // E
    int* hist    = csr_src + E;                  // N
    int* tmp     = hist + N;                     // N
    int* fillc   = tmp + N;                      // N
    int* bsums   = fillc + N;                    // 256
    // total ~58.5 MB

    const int nScanBlocks = (N + THREADS - 1) / THREADS;   // 196

    hipMemsetAsync(hist, 0, (size_t)N * sizeof(int), stream);
    hipMemsetAsync(fillc, 0, (size_t)N * sizeof(int), stream);

    // --- CSR build ---
    hist_k<<<(E + THREADS - 1) / THREADS, THREADS, 0, stream>>>(dstv, hist, E);
    scan_block<<<nScanBlocks, THREADS, 0, stream>>>(hist, tmp, bsums, N);
    scan_bsums<<<1, THREADS, 0, stream>>>(bsums, nScanBlocks);
    scan_finish<<<(N + THREADS) / THREADS, THREADS, 0, stream>>>(tmp, hist, bsums, rowptr, N, E);
    csr_fill<<<(E + THREADS - 1) / THREADS, THREADS, 0, stream>>>(src, dstv, rowptr, fillc, csr_src, E);

    dim3 g128((N + 31) / 32, 2);
    dim3 g64((N + 31) / 32, 1);

    // --- layer 1 ---
    sage_gemm<128><<<g128, THREADS, 0, stream>>>(x, Wl1, nullptr, nullptr, nullptr, A, N, 0);   // p1
    sage_gather<128, 32><<<(N * 32 + THREADS - 1) / THREADS, THREADS, 0, stream>>>(A, rowptr, csr_src, B, N);  // agg1
    sage_gemm<128><<<g128, THREADS, 0, stream>>>(x, Wr1, b1, B, rowptr, A, N, 1);               // h (overwrites p1)

    // --- layer 2 ---
    sage_gemm<64><<<g64, THREADS, 0, stream>>>(A, Wl2, nullptr, nullptr, nullptr, B, N, 0);     // p2 (overwrites agg1)
    sage_gather<64, 16><<<(N * 16 + THREADS - 1) / THREADS, THREADS, 0, stream>>>(B, rowptr, csr_src, out, N); // agg2 -> out
    sage_gemm<64><<<g64, THREADS, 0, stream>>>(A, Wr2, b2, out, rowptr, out, N, 0);             // final (in-place agg)
}

// Round 3
// 433.995 us; speedup vs baseline: 2.9948x; 1.2591x over previous
//
#include <hip/hip_runtime.h>
#include <hip/hip_bf16.h>

// GraphSAGE 2-layer forward.
// R3 changes vs R2:
//  1) csr_fill (110us, 102MB write-through from scattered 4B stores) replaced by
//     two-level dst-partition: bucket_part (block-exclusive reserved runs) +
//     bucket_sort (one block owns one 256-dst bucket -> exclusive csr region,
//     full-line write-backs).
//  2) p1/p2 gather tables stored as bf16 (halves gather FETCH); mean division
//     folded into gather; fp32 accumulation throughout.

#define THREADS 256

static __device__ __forceinline__ unsigned short f2bf(float f) {
    unsigned int u = __float_as_uint(f);
    u = (u + 0x7fffu + ((u >> 16) & 1u)) >> 16;   // round-to-nearest-even
    return (unsigned short)u;
}

// ---------------------------------------------------------------------------
// Global per-dst degree histogram
__global__ __launch_bounds__(THREADS)
void hist_k(const int* __restrict__ dst, int* __restrict__ hist, int E) {
    int e = blockIdx.x * THREADS + threadIdx.x;
    if (e < E) atomicAdd(&hist[dst[e]], 1);
}

// Per-block inclusive scan (256/block) + block sums
__global__ __launch_bounds__(THREADS)
void scan_block(const int* __restrict__ in, int* __restrict__ tmp,
                int* __restrict__ bsums, int n) {
    __shared__ int s[THREADS];
    int i = blockIdx.x * THREADS + threadIdx.x;
    int v = (i < n) ? in[i] : 0;
    s[threadIdx.x] = v;
    __syncthreads();
    for (int off = 1; off < THREADS; off <<= 1) {
        int t = (threadIdx.x >= off) ? s[threadIdx.x - off] : 0;
        __syncthreads();
        s[threadIdx.x] += t;
        __syncthreads();
    }
    if (i < n) tmp[i] = s[threadIdx.x];
    if (threadIdx.x == THREADS - 1) bsums[blockIdx.x] = s[threadIdx.x];
}

__global__ __launch_bounds__(THREADS)
void scan_bsums(int* __restrict__ bsums, int nb) {
    __shared__ int s[THREADS];
    int v = (threadIdx.x < nb) ? bsums[threadIdx.x] : 0;
    s[threadIdx.x] = v;
    __syncthreads();
    for (int off = 1; off < THREADS; off <<= 1) {
        int t = (threadIdx.x >= off) ? s[threadIdx.x - off] : 0;
        __syncthreads();
        s[threadIdx.x] += t;
        __syncthreads();
    }
    int excl = (threadIdx.x == 0) ? 0 : s[threadIdx.x - 1];
    if (threadIdx.x < nb) bsums[threadIdx.x] = excl;
}

__global__ __launch_bounds__(THREADS)
void scan_finish(const int* __restrict__ tmp, const int* __restrict__ hist,
                 const int* __restrict__ bsums, int* __restrict__ rowptr,
                 int n, int E) {
    int i = blockIdx.x * THREADS + threadIdx.x;
    if (i < n) rowptr[i] = tmp[i] - hist[i] + bsums[i / THREADS];
    if (i == n) rowptr[n] = E;
}

// ---------------------------------------------------------------------------
// Coarse bucket (dst>>8) histogram: LDS-privatized, few global atomics
__global__ __launch_bounds__(THREADS)
void bucket_hist(const int* __restrict__ dst, int* __restrict__ bhist,
                 int E, int NB) {
    __shared__ int lh[THREADS];
    if (threadIdx.x < NB) lh[threadIdx.x] = 0;
    __syncthreads();
    int stride = gridDim.x * THREADS;
    for (int e = blockIdx.x * THREADS + threadIdx.x; e < E; e += stride)
        atomicAdd(&lh[dst[e] >> 8], 1);
    __syncthreads();
    if (threadIdx.x < NB && lh[threadIdx.x])
        atomicAdd(&bhist[threadIdx.x], lh[threadIdx.x]);
}

// Single-block scan of bucket counts -> bucket_base[NB+1], init bucketFill
__global__ __launch_bounds__(THREADS)
void bucket_scan(const int* __restrict__ bhist, int* __restrict__ bucket_base,
                 int* __restrict__ bucketFill, int NB, int E) {
    __shared__ int s[THREADS];
    int v = (threadIdx.x < NB) ? bhist[threadIdx.x] : 0;
    s[threadIdx.x] = v;
    __syncthreads();
    for (int off = 1; off < THREADS; off <<= 1) {
        int t = (threadIdx.x >= off) ? s[threadIdx.x - off] : 0;
        __syncthreads();
        s[threadIdx.x] += t;
        __syncthreads();
    }
    int excl = (threadIdx.x == 0) ? 0 : s[threadIdx.x - 1];
    if (threadIdx.x < NB) {
        bucket_base[threadIdx.x] = excl;
        bucketFill[threadIdx.x] = excl;
    }
    if (threadIdx.x == 0) bucket_base[NB] = E;
}

// Level-1 partition: each block owns a contiguous edge range, reserves
// block-exclusive runs per bucket (full lines assemble in one L2).
__global__ __launch_bounds__(THREADS)
void bucket_part(const int* __restrict__ src, const int* __restrict__ dst,
                 int* __restrict__ bucketFill, int2* __restrict__ pairs,
                 int E, int NB) {
    __shared__ int lh[THREADS];
    __shared__ int lbase[THREADS];
    __shared__ int lo[THREADS];
    int chunk = (E + gridDim.x - 1) / gridDim.x;
    int e0 = blockIdx.x * chunk;
    int e1 = min(E, e0 + chunk);
    if (threadIdx.x < NB) { lh[threadIdx.x] = 0; lo[threadIdx.x] = 0; }
    __syncthreads();
    for (int e = e0 + threadIdx.x; e < e1; e += THREADS)
        atomicAdd(&lh[dst[e] >> 8], 1);
    __syncthreads();
    if (threadIdx.x < NB)
        lbase[threadIdx.x] = lh[threadIdx.x] ? atomicAdd(&bucketFill[threadIdx.x], lh[threadIdx.x]) : 0;
    __syncthreads();
    for (int e = e0 + threadIdx.x; e < e1; e += THREADS) {
        int d = dst[e];
        int bk = d >> 8;
        int pos = lbase[bk] + atomicAdd(&lo[bk], 1);
        pairs[pos] = make_int2(src[e], d);
    }
}

// Level-2: one block per bucket, exclusive 256-dst range -> exclusive
// csr_src region, full-line write-backs.
__global__ __launch_bounds__(THREADS)
void bucket_sort(const int2* __restrict__ pairs, const int* __restrict__ bucket_base,
                 const int* __restrict__ rowptr, int* __restrict__ csr_src, int N) {
    __shared__ int loff[THREADS];
    int b = blockIdx.x;
    int id = (b << 8) + threadIdx.x;
    loff[threadIdx.x] = (id < N) ? rowptr[id] : 0;
    __syncthreads();
    int s0 = bucket_base[b], s1 = bucket_base[b + 1];
    for (int i = s0 + threadIdx.x; i < s1; i += THREADS) {
        int2 pr = pairs[i];
        int pos = atomicAdd(&loff[pr.y & 255], 1);
        csr_src[pos] = pr.x;
    }
}

// ---------------------------------------------------------------------------
// Gather-reduce over bf16 table, fp32 accumulate, writes MEAN (fp32).
// LANES = DIM/8; each lane covers 8 bf16 elems (16B).
template<int DIM, int LANES>
__global__ __launch_bounds__(THREADS)
void sage_gather(const unsigned short* __restrict__ p, const int* __restrict__ rowptr,
                 const int* __restrict__ csr_src, float* __restrict__ agg, int N) {
    constexpr int GPER = THREADS / LANES;
    int g = blockIdx.x * GPER + threadIdx.x / LANES;
    if (g >= N) return;
    int lane = threadIdx.x % LANES;
    int start = rowptr[g], end = rowptr[g + 1];
    float acc[8] = {0.f, 0.f, 0.f, 0.f, 0.f, 0.f, 0.f, 0.f};
    for (int base = start; base < end; base += LANES) {
        int my = base + lane;
        int sv = (my < end) ? csr_src[my] : 0;
        int m = min(LANES, end - base);
        #pragma unroll 4
        for (int j = 0; j < m; ++j) {
            int s = __shfl(sv, j, LANES);
            uint4 v = *(const uint4*)&p[(size_t)s * DIM + lane * 8];
            acc[0] += __uint_as_float(v.x << 16);
            acc[1] += __uint_as_float(v.x & 0xffff0000u);
            acc[2] += __uint_as_float(v.y << 16);
            acc[3] += __uint_as_float(v.y & 0xffff0000u);
            acc[4] += __uint_as_float(v.z << 16);
            acc[5] += __uint_as_float(v.z & 0xffff0000u);
            acc[6] += __uint_as_float(v.w << 16);
            acc[7] += __uint_as_float(v.w & 0xffff0000u);
        }
    }
    float rc = 1.0f / fmaxf((float)(end - start), 1.0f);
    float4 o0 = make_float4(acc[0] * rc, acc[1] * rc, acc[2] * rc, acc[3] * rc);
    float4 o1 = make_float4(acc[4] * rc, acc[5] * rc, acc[6] * rc, acc[7] * rc);
    *(float4*)&agg[(size_t)g * DIM + lane * 8] = o0;
    *(float4*)&agg[(size_t)g * DIM + lane * 8 + 4] = o1;
}

// ---------------------------------------------------------------------------
// Fused GEMM: out[n][c] = optrelu( X[n,:]@W[c,:] + bias[c] + aggmean[n][c] )
// OBF: store bf16 (for gather tables) else fp32.
template<int DOUT, bool OBF>
__global__ __launch_bounds__(THREADS)
void sage_gemm(const float* __restrict__ X, const float* __restrict__ W,
               const float* __restrict__ bias, const float* __restrict__ agg,
               void* __restrict__ outv, int N, int doRelu) {
    constexpr int COLS = 64;
    constexpr int ROWS = 32;
    __shared__ float ws[128][COLS + 4];
    __shared__ float xs[ROWS][128 + 4];

    const int tid = threadIdx.x;
    const int r0 = blockIdx.x * ROWS;
    const int colbase = blockIdx.y * COLS;

    for (int i = tid; i < COLS * 128; i += THREADS) {
        int col = i >> 7, k = i & 127;
        ws[k][col] = W[(size_t)(colbase + col) * 128 + k];
    }
    for (int i = tid; i < ROWS * 32; i += THREADS) {
        int row = i >> 5, kq = i & 31;
        int n = r0 + row;
        float4 v = make_float4(0.f, 0.f, 0.f, 0.f);
        if (n < N) v = *(const float4*)&X[(size_t)n * 128 + kq * 4];
        *(float4*)&xs[row][kq * 4] = v;
    }
    __syncthreads();

    const int c0 = (tid & 15) * 4;
    const int rb = (tid >> 4) * 2;
    float acc[2][4] = {{0.f,0.f,0.f,0.f},{0.f,0.f,0.f,0.f}};

    for (int k = 0; k < 128; k += 4) {
        float4 x0 = *(const float4*)&xs[rb][k];
        float4 x1 = *(const float4*)&xs[rb + 1][k];
        #pragma unroll
        for (int i = 0; i < 4; ++i) {
            float4 w4 = *(const float4*)&ws[k + i][c0];
            float xv0 = (&x0.x)[i];
            float xv1 = (&x1.x)[i];
            acc[0][0] += xv0 * w4.x; acc[0][1] += xv0 * w4.y;
            acc[0][2] += xv0 * w4.z; acc[0][3] += xv0 * w4.w;
            acc[1][0] += xv1 * w4.x; acc[1][1] += xv1 * w4.y;
            acc[1][2] += xv1 * w4.z; acc[1][3] += xv1 * w4.w;
        }
    }

    #pragma unroll
    for (int r = 0; r < 2; ++r) {
        int n = r0 + rb + r;
        if (n >= N) continue;
        int c = colbase + c0;
        float4 o = make_float4(acc[r][0], acc[r][1], acc[r][2], acc[r][3]);
        if (bias) {
            o.x += bias[c];     o.y += bias[c + 1];
            o.z += bias[c + 2]; o.w += bias[c + 3];
        }
        if (agg) {
            float4 a = *(const float4*)&agg[(size_t)n * DOUT + c];
            o.x += a.x; o.y += a.y; o.z += a.z; o.w += a.w;
        }
        if (doRelu) {
            o.x = fmaxf(o.x, 0.f); o.y = fmaxf(o.y, 0.f);
            o.z = fmaxf(o.z, 0.f); o.w = fmaxf(o.w, 0.f);
        }
        if (OBF) {
            ushort4 u;
            u.x = f2bf(o.x); u.y = f2bf(o.y); u.z = f2bf(o.z); u.w = f2bf(o.w);
            *(ushort4*)&((unsigned short*)outv)[(size_t)n * DOUT + c] = u;
        } else {
            *(float4*)&((float*)outv)[(size_t)n * DOUT + c] = o;
        }
    }
}

// ---------------------------------------------------------------------------
extern "C" void kernel_launch(void* const* d_in, const int* in_sizes, int n_in,
                              void* d_out, int out_size, void* d_ws, size_t ws_size,
                              hipStream_t stream) {
    const float* x   = (const float*)d_in[0];
    const int* edges = (const int*)d_in[1];
    const float* Wl1 = (const float*)d_in[2];
    const float* Wr1 = (const float*)d_in[3];
    const float* b1  = (const float*)d_in[4];
    const float* Wl2 = (const float*)d_in[5];
    const float* Wr2 = (const float*)d_in[6];
    const float* b2  = (const float*)d_in[7];
    float* out = (float*)d_out;

    const int N = in_sizes[0] / 128;     // 50000
    const int E = in_sizes[1] / 2;       // 1600000
    const int NB = (N + 255) >> 8;       // 196 coarse buckets
    const int* src = edges;
    const int* dstv = edges + E;

    // Workspace layout
    char* wsp = (char*)d_ws;
    unsigned short* p1 = (unsigned short*)wsp;              wsp += (size_t)N * 128 * 2;  // 12.8 MB
    float* agg1        = (float*)wsp;                       wsp += (size_t)N * 128 * 4;  // 25.6 MB
    float* h           = (float*)wsp;                       wsp += (size_t)N * 128 * 4;  // 25.6 MB
    unsigned short* p2 = (unsigned short*)wsp;              wsp += (size_t)N * 64 * 2;   //  6.4 MB
    int2* pairs        = (int2*)wsp;                        wsp += (size_t)E * 8;        // 12.8 MB
    int* csr_src       = (int*)wsp;                         wsp += (size_t)E * 4;        //  6.4 MB
    int* rowptr        = (int*)wsp;                         wsp += (size_t)(N + 1) * 4;
    int* hist          = (int*)wsp;                         wsp += (size_t)N * 4;
    int* bhist         = (int*)wsp;                         wsp += (size_t)NB * 4;
    int* tmp           = (int*)wsp;                         wsp += (size_t)N * 4;
    int* bucket_base   = (int*)wsp;                         wsp += (size_t)(NB + 1) * 4;
    int* bucketFill    = (int*)wsp;                         wsp += (size_t)NB * 4;
    int* bsums         = (int*)wsp;                         wsp += 256 * 4;

    const int nScanBlocks = (N + THREADS - 1) / THREADS;

    // hist and bhist are adjacent -> one memset
    hipMemsetAsync(hist, 0, ((size_t)N + NB) * sizeof(int), stream);

    // --- CSR build ---
    hist_k<<<(E + THREADS - 1) / THREADS, THREADS, 0, stream>>>(dstv, hist, E);
    scan_block<<<nScanBlocks, THREADS, 0, stream>>>(hist, tmp, bsums, N);
    scan_bsums<<<1, THREADS, 0, stream>>>(bsums, nScanBlocks);
    scan_finish<<<(N + THREADS) / THREADS, THREADS, 0, stream>>>(tmp, hist, bsums, rowptr, N, E);
    bucket_hist<<<400, THREADS, 0, stream>>>(dstv, bhist, E, NB);
    bucket_scan<<<1, THREADS, 0, stream>>>(bhist, bucket_base, bucketFill, NB, E);
    bucket_part<<<512, THREADS, 0, stream>>>(src, dstv, bucketFill, pairs, E, NB);
    bucket_sort<<<NB, THREADS, 0, stream>>>(pairs, bucket_base, rowptr, csr_src, N);

    dim3 g128((N + 31) / 32, 2);
    dim3 g64((N + 31) / 32, 1);

    // --- layer 1 ---
    sage_gemm<128, true><<<g128, THREADS, 0, stream>>>(x, Wl1, nullptr, nullptr, p1, N, 0);
    sage_gather<128, 16><<<(N + 15) / 16, THREADS, 0, stream>>>(p1, rowptr, csr_src, agg1, N);
    sage_gemm<128, false><<<g128, THREADS, 0, stream>>>(x, Wr1, b1, agg1, h, N, 1);

    // --- layer 2 ---
    sage_gemm<64, true><<<g64, THREADS, 0, stream>>>(h, Wl2, nullptr, nullptr, p2, N, 0);
    sage_gather<64, 8><<<(N + 31) / 32, THREADS, 0, stream>>>(p2, rowptr, csr_src, out, N);
    sage_gemm<64, false><<<g64, THREADS, 0, stream>>>(h, Wr2, b2, out, out, N, 0);
}

// Round 4
// 380.114 us; speedup vs baseline: 3.4193x; 1.1417x over previous
//
#include <hip/hip_runtime.h>
#include <hip/hip_bf16.h>

// GraphSAGE 2-layer forward.
// R4 changes vs R3:
//  1) hist_k (70us, 50MB atomic write-through) + 3-kernel scan chain + big
//     memset ELIMINATED: bucket_sort now builds each bucket's 256-entry degree
//     histogram in LDS, scans it in LDS, writes rowptr coalesced, then fills.
//  2) gather inner loop split into fully-unrolled full batches (16/8 deep)
//     for higher memory-level parallelism.

#define THREADS 256

static __device__ __forceinline__ unsigned short f2bf(float f) {
    unsigned int u = __float_as_uint(f);
    u = (u + 0x7fffu + ((u >> 16) & 1u)) >> 16;   // round-to-nearest-even
    return (unsigned short)u;
}

// ---------------------------------------------------------------------------
// Coarse bucket (dst>>8) histogram: LDS-privatized
__global__ __launch_bounds__(THREADS)
void bucket_hist(const int* __restrict__ dst, int* __restrict__ bhist,
                 int E, int NB) {
    __shared__ int lh[THREADS];
    if (threadIdx.x < NB) lh[threadIdx.x] = 0;
    __syncthreads();
    int stride = gridDim.x * THREADS;
    for (int e = blockIdx.x * THREADS + threadIdx.x; e < E; e += stride)
        atomicAdd(&lh[dst[e] >> 8], 1);
    __syncthreads();
    if (threadIdx.x < NB && lh[threadIdx.x])
        atomicAdd(&bhist[threadIdx.x], lh[threadIdx.x]);
}

// Single-block scan of bucket counts -> bucket_base[NB+1], init bucketFill,
// and set rowptr[N] = E (bucket_sort writes rowptr[0..N-1]).
__global__ __launch_bounds__(THREADS)
void bucket_scan(const int* __restrict__ bhist, int* __restrict__ bucket_base,
                 int* __restrict__ bucketFill, int* __restrict__ rowptr,
                 int NB, int N, int E) {
    __shared__ int s[THREADS];
    int v = (threadIdx.x < NB) ? bhist[threadIdx.x] : 0;
    s[threadIdx.x] = v;
    __syncthreads();
    for (int off = 1; off < THREADS; off <<= 1) {
        int t = (threadIdx.x >= off) ? s[threadIdx.x - off] : 0;
        __syncthreads();
        s[threadIdx.x] += t;
        __syncthreads();
    }
    int excl = (threadIdx.x == 0) ? 0 : s[threadIdx.x - 1];
    if (threadIdx.x < NB) {
        bucket_base[threadIdx.x] = excl;
        bucketFill[threadIdx.x] = excl;
    }
    if (threadIdx.x == 0) {
        bucket_base[NB] = E;
        rowptr[N] = E;
    }
}

// Level-1 partition: each block owns a contiguous edge range, reserves
// block-exclusive runs per bucket -> (src,dst) pairs grouped by bucket.
__global__ __launch_bounds__(THREADS)
void bucket_part(const int* __restrict__ src, const int* __restrict__ dst,
                 int* __restrict__ bucketFill, int2* __restrict__ pairs,
                 int E, int NB) {
    __shared__ int lh[THREADS];
    __shared__ int lbase[THREADS];
    __shared__ int lo[THREADS];
    int chunk = (E + gridDim.x - 1) / gridDim.x;
    int e0 = blockIdx.x * chunk;
    int e1 = min(E, e0 + chunk);
    if (threadIdx.x < NB) { lh[threadIdx.x] = 0; lo[threadIdx.x] = 0; }
    __syncthreads();
    for (int e = e0 + threadIdx.x; e < e1; e += THREADS)
        atomicAdd(&lh[dst[e] >> 8], 1);
    __syncthreads();
    if (threadIdx.x < NB)
        lbase[threadIdx.x] = lh[threadIdx.x] ? atomicAdd(&bucketFill[threadIdx.x], lh[threadIdx.x]) : 0;
    __syncthreads();
    for (int e = e0 + threadIdx.x; e < e1; e += THREADS) {
        int d = dst[e];
        int bk = d >> 8;
        int pos = lbase[bk] + atomicAdd(&lo[bk], 1);
        pairs[pos] = make_int2(src[e], d);
    }
}

// Level-2: one block per bucket. Builds per-dst degree hist in LDS, scans it
// in LDS (-> rowptr, coalesced), then scatters src ids into the bucket's
// exclusive csr region (full-line write-backs).
__global__ __launch_bounds__(THREADS)
void bucket_sort(const int2* __restrict__ pairs, const int* __restrict__ bucket_base,
                 int* __restrict__ rowptr, int* __restrict__ csr_src, int N) {
    __shared__ int lhist[THREADS];
    __shared__ int lscan[THREADS];
    __shared__ int loff[THREADS];
    int b = blockIdx.x;
    int s0 = bucket_base[b], s1 = bucket_base[b + 1];
    lhist[threadIdx.x] = 0;
    __syncthreads();
    for (int i = s0 + threadIdx.x; i < s1; i += THREADS)
        atomicAdd(&lhist[pairs[i].y & 255], 1);
    __syncthreads();
    int v = lhist[threadIdx.x];
    lscan[threadIdx.x] = v;
    __syncthreads();
    for (int off = 1; off < THREADS; off <<= 1) {
        int t = (threadIdx.x >= off) ? lscan[threadIdx.x - off] : 0;
        __syncthreads();
        lscan[threadIdx.x] += t;
        __syncthreads();
    }
    int base = s0 + lscan[threadIdx.x] - v;   // exclusive prefix within bucket
    int id = (b << 8) + threadIdx.x;
    if (id < N) rowptr[id] = base;
    loff[threadIdx.x] = base;
    __syncthreads();
    for (int i = s0 + threadIdx.x; i < s1; i += THREADS) {
        int2 pr = pairs[i];
        int pos = atomicAdd(&loff[pr.y & 255], 1);
        csr_src[pos] = pr.x;
    }
}

// ---------------------------------------------------------------------------
// Gather-reduce over bf16 table, fp32 accumulate, writes MEAN (fp32).
// LANES = DIM/8; each lane covers 8 bf16 elems (16B). Full batches are
// fully unrolled (LANES outstanding uint4 loads per lane).
template<int DIM, int LANES>
__global__ __launch_bounds__(THREADS)
void sage_gather(const unsigned short* __restrict__ p, const int* __restrict__ rowptr,
                 const int* __restrict__ csr_src, float* __restrict__ agg, int N) {
    constexpr int GPER = THREADS / LANES;
    int g = blockIdx.x * GPER + threadIdx.x / LANES;
    if (g >= N) return;
    int lane = threadIdx.x % LANES;
    int start = rowptr[g], end = rowptr[g + 1];
    float acc[8] = {0.f, 0.f, 0.f, 0.f, 0.f, 0.f, 0.f, 0.f};
    int base = start;
    for (; base + LANES <= end; base += LANES) {
        int sv = csr_src[base + lane];
        #pragma unroll
        for (int j = 0; j < LANES; ++j) {
            int s = __shfl(sv, j, LANES);
            uint4 v = *(const uint4*)&p[(size_t)s * DIM + lane * 8];
            acc[0] += __uint_as_float(v.x << 16);
            acc[1] += __uint_as_float(v.x & 0xffff0000u);
            acc[2] += __uint_as_float(v.y << 16);
            acc[3] += __uint_as_float(v.y & 0xffff0000u);
            acc[4] += __uint_as_float(v.z << 16);
            acc[5] += __uint_as_float(v.z & 0xffff0000u);
            acc[6] += __uint_as_float(v.w << 16);
            acc[7] += __uint_as_float(v.w & 0xffff0000u);
        }
    }
    if (base < end) {
        int my = base + lane;
        int sv = (my < end) ? csr_src[my] : 0;
        int m = end - base;
        for (int j = 0; j < m; ++j) {
            int s = __shfl(sv, j, LANES);
            uint4 v = *(const uint4*)&p[(size_t)s * DIM + lane * 8];
            acc[0] += __uint_as_float(v.x << 16);
            acc[1] += __uint_as_float(v.x & 0xffff0000u);
            acc[2] += __uint_as_float(v.y << 16);
            acc[3] += __uint_as_float(v.y & 0xffff0000u);
            acc[4] += __uint_as_float(v.z << 16);
            acc[5] += __uint_as_float(v.z & 0xffff0000u);
            acc[6] += __uint_as_float(v.w << 16);
            acc[7] += __uint_as_float(v.w & 0xffff0000u);
        }
    }
    float rc = 1.0f / fmaxf((float)(end - start), 1.0f);
    float4 o0 = make_float4(acc[0] * rc, acc[1] * rc, acc[2] * rc, acc[3] * rc);
    float4 o1 = make_float4(acc[4] * rc, acc[5] * rc, acc[6] * rc, acc[7] * rc);
    *(float4*)&agg[(size_t)g * DIM + lane * 8] = o0;
    *(float4*)&agg[(size_t)g * DIM + lane * 8 + 4] = o1;
}

// ---------------------------------------------------------------------------
// Fused GEMM: out[n][c] = optrelu( X[n,:]@W[c,:] + bias[c] + aggmean[n][c] )
// OBF: store bf16 (for gather tables) else fp32.
template<int DOUT, bool OBF>
__global__ __launch_bounds__(THREADS)
void sage_gemm(const float* __restrict__ X, const float* __restrict__ W,
               const float* __restrict__ bias, const float* __restrict__ agg,
               void* __restrict__ outv, int N, int doRelu) {
    constexpr int COLS = 64;
    constexpr int ROWS = 32;
    __shared__ float ws[128][COLS + 4];
    __shared__ float xs[ROWS][128 + 4];

    const int tid = threadIdx.x;
    const int r0 = blockIdx.x * ROWS;
    const int colbase = blockIdx.y * COLS;

    for (int i = tid; i < COLS * 128; i += THREADS) {
        int col = i >> 7, k = i & 127;
        ws[k][col] = W[(size_t)(colbase + col) * 128 + k];
    }
    for (int i = tid; i < ROWS * 32; i += THREADS) {
        int row = i >> 5, kq = i & 31;
        int n = r0 + row;
        float4 v = make_float4(0.f, 0.f, 0.f, 0.f);
        if (n < N) v = *(const float4*)&X[(size_t)n * 128 + kq * 4];
        *(float4*)&xs[row][kq * 4] = v;
    }
    __syncthreads();

    const int c0 = (tid & 15) * 4;
    const int rb = (tid >> 4) * 2;
    float acc[2][4] = {{0.f,0.f,0.f,0.f},{0.f,0.f,0.f,0.f}};

    for (int k = 0; k < 128; k += 4) {
        float4 x0 = *(const float4*)&xs[rb][k];
        float4 x1 = *(const float4*)&xs[rb + 1][k];
        #pragma unroll
        for (int i = 0; i < 4; ++i) {
            float4 w4 = *(const float4*)&ws[k + i][c0];
            float xv0 = (&x0.x)[i];
            float xv1 = (&x1.x)[i];
            acc[0][0] += xv0 * w4.x; acc[0][1] += xv0 * w4.y;
            acc[0][2] += xv0 * w4.z; acc[0][3] += xv0 * w4.w;
            acc[1][0] += xv1 * w4.x; acc[1][1] += xv1 * w4.y;
            acc[1][2] += xv1 * w4.z; acc[1][3] += xv1 * w4.w;
        }
    }

    #pragma unroll
    for (int r = 0; r < 2; ++r) {
        int n = r0 + rb + r;
        if (n >= N) continue;
        int c = colbase + c0;
        float4 o = make_float4(acc[r][0], acc[r][1], acc[r][2], acc[r][3]);
        if (bias) {
            o.x += bias[c];     o.y += bias[c + 1];
            o.z += bias[c + 2]; o.w += bias[c + 3];
        }
        if (agg) {
            float4 a = *(const float4*)&agg[(size_t)n * DOUT + c];
            o.x += a.x; o.y += a.y; o.z += a.z; o.w += a.w;
        }
        if (doRelu) {
            o.x = fmaxf(o.x, 0.f); o.y = fmaxf(o.y, 0.f);
            o.z = fmaxf(o.z, 0.f); o.w = fmaxf(o.w, 0.f);
        }
        if (OBF) {
            ushort4 u;
            u.x = f2bf(o.x); u.y = f2bf(o.y); u.z = f2bf(o.z); u.w = f2bf(o.w);
            *(ushort4*)&((unsigned short*)outv)[(size_t)n * DOUT + c] = u;
        } else {
            *(float4*)&((float*)outv)[(size_t)n * DOUT + c] = o;
        }
    }
}

// ---------------------------------------------------------------------------
extern "C" void kernel_launch(void* const* d_in, const int* in_sizes, int n_in,
                              void* d_out, int out_size, void* d_ws, size_t ws_size,
                              hipStream_t stream) {
    const float* x   = (const float*)d_in[0];
    const int* edges = (const int*)d_in[1];
    const float* Wl1 = (const float*)d_in[2];
    const float* Wr1 = (const float*)d_in[3];
    const float* b1  = (const float*)d_in[4];
    const float* Wl2 = (const float*)d_in[5];
    const float* Wr2 = (const float*)d_in[6];
    const float* b2  = (const float*)d_in[7];
    float* out = (float*)d_out;

    const int N = in_sizes[0] / 128;     // 50000
    const int E = in_sizes[1] / 2;       // 1600000
    const int NB = (N + 255) >> 8;       // 196 coarse buckets
    const int* src = edges;
    const int* dstv = edges + E;

    // Workspace layout
    char* wsp = (char*)d_ws;
    unsigned short* p1 = (unsigned short*)wsp;              wsp += (size_t)N * 128 * 2;  // 12.8 MB
    float* agg1        = (float*)wsp;                       wsp += (size_t)N * 128 * 4;  // 25.6 MB
    float* h           = (float*)wsp;                       wsp += (size_t)N * 128 * 4;  // 25.6 MB
    unsigned short* p2 = (unsigned short*)wsp;              wsp += (size_t)N * 64 * 2;   //  6.4 MB
    int2* pairs        = (int2*)wsp;                        wsp += (size_t)E * 8;        // 12.8 MB
    int* csr_src       = (int*)wsp;                         wsp += (size_t)E * 4;        //  6.4 MB
    int* rowptr        = (int*)wsp;                         wsp += (size_t)(N + 1) * 4;
    int* bhist         = (int*)wsp;                         wsp += (size_t)NB * 4;
    int* bucket_base   = (int*)wsp;                         wsp += (size_t)(NB + 1) * 4;
    int* bucketFill    = (int*)wsp;                         wsp += (size_t)NB * 4;

    hipMemsetAsync(bhist, 0, (size_t)NB * sizeof(int), stream);

    // --- CSR build (no global per-dst histogram, no global scan chain) ---
    bucket_hist<<<400, THREADS, 0, stream>>>(dstv, bhist, E, NB);
    bucket_scan<<<1, THREADS, 0, stream>>>(bhist, bucket_base, bucketFill, rowptr, NB, N, E);
    bucket_part<<<512, THREADS, 0, stream>>>(src, dstv, bucketFill, pairs, E, NB);
    bucket_sort<<<NB, THREADS, 0, stream>>>(pairs, bucket_base, rowptr, csr_src, N);

    dim3 g128((N + 31) / 32, 2);
    dim3 g64((N + 31) / 32, 1);

    // --- layer 1 ---
    sage_gemm<128, true><<<g128, THREADS, 0, stream>>>(x, Wl1, nullptr, nullptr, p1, N, 0);
    sage_gather<128, 16><<<(N + 15) / 16, THREADS, 0, stream>>>(p1, rowptr, csr_src, agg1, N);
    sage_gemm<128, false><<<g128, THREADS, 0, stream>>>(x, Wr1, b1, agg1, h, N, 1);

    // --- layer 2 ---
    sage_gemm<64, true><<<g64, THREADS, 0, stream>>>(h, Wl2, nullptr, nullptr, p2, N, 0);
    sage_gather<64, 8><<<(N + 31) / 32, THREADS, 0, stream>>>(p2, rowptr, csr_src, out, N);
    sage_gemm<64, false><<<g64, THREADS, 0, stream>>>(h, Wr2, b2, out, out, N, 0);
}

// Round 5
// 327.215 us; speedup vs baseline: 3.9721x; 1.1617x over previous
//
#include <hip/hip_runtime.h>
#include <hip/hip_bf16.h>

// GraphSAGE 2-layer forward.
// R5 changes vs R4:
//  1) All four GEMMs -> MFMA bf16 (16x16x32), B-fragments VGPR-resident,
//     weights pre-cast to bf16 (cast_w). fp32 vector GEMMs eliminated.
//  2) GEMM epilogues fused into gathers: gather_h computes h=relu(mean+r1)
//     and stores bf16; gather_out computes out=mean+r2 (final fp32).
//  3) N<65536: pairs packed to 4B (src|dlow<<16), csr_src as ushort ->
//     halves CSR-build and gather index traffic.

#define THREADS 256

typedef __bf16 bf16x8 __attribute__((ext_vector_type(8)));
typedef float floatx4 __attribute__((ext_vector_type(4)));

union ABfrag { bf16x8 v; unsigned short u[8]; uint4 q; };

static __device__ __forceinline__ unsigned short f2bf(float f) {
    unsigned int u = __float_as_uint(f);
    u = (u + 0x7fffu + ((u >> 16) & 1u)) >> 16;   // round-to-nearest-even
    return (unsigned short)u;
}

// ---------------------------------------------------------------------------
// Cast the four weight matrices to bf16 into one packed buffer:
// [Wl1 16384 | Wr1 16384 | Wl2 8192 | Wr2 8192]
__global__ __launch_bounds__(THREADS)
void cast_w(const float* __restrict__ a, const float* __restrict__ b,
            const float* __restrict__ c, const float* __restrict__ d,
            unsigned short* __restrict__ o) {
    int i = blockIdx.x * THREADS + threadIdx.x;
    if (i >= 49152) return;
    float v;
    if (i < 16384) v = a[i];
    else if (i < 32768) v = b[i - 16384];
    else if (i < 40960) v = c[i - 32768];
    else v = d[i - 40960];
    o[i] = f2bf(v);
}

// ---------------------------------------------------------------------------
// Coarse bucket (dst>>8) histogram: LDS-privatized
__global__ __launch_bounds__(THREADS)
void bucket_hist(const int* __restrict__ dst, int* __restrict__ bhist,
                 int E, int NB) {
    __shared__ int lh[THREADS];
    if (threadIdx.x < NB) lh[threadIdx.x] = 0;
    __syncthreads();
    int stride = gridDim.x * THREADS;
    for (int e = blockIdx.x * THREADS + threadIdx.x; e < E; e += stride)
        atomicAdd(&lh[dst[e] >> 8], 1);
    __syncthreads();
    if (threadIdx.x < NB && lh[threadIdx.x])
        atomicAdd(&bhist[threadIdx.x], lh[threadIdx.x]);
}

// Single-block scan of bucket counts -> bucket_base[NB+1], init bucketFill,
// rowptr[N] = E.
__global__ __launch_bounds__(THREADS)
void bucket_scan(const int* __restrict__ bhist, int* __restrict__ bucket_base,
                 int* __restrict__ bucketFill, int* __restrict__ rowptr,
                 int NB, int N, int E) {
    __shared__ int s[THREADS];
    int v = (threadIdx.x < NB) ? bhist[threadIdx.x] : 0;
    s[threadIdx.x] = v;
    __syncthreads();
    for (int off = 1; off < THREADS; off <<= 1) {
        int t = (threadIdx.x >= off) ? s[threadIdx.x - off] : 0;
        __syncthreads();
        s[threadIdx.x] += t;
        __syncthreads();
    }
    int excl = (threadIdx.x == 0) ? 0 : s[threadIdx.x - 1];
    if (threadIdx.x < NB) {
        bucket_base[threadIdx.x] = excl;
        bucketFill[threadIdx.x] = excl;
    }
    if (threadIdx.x == 0) {
        bucket_base[NB] = E;
        rowptr[N] = E;
    }
}

// Level-1 partition: block-exclusive reserved runs per 256-dst bucket.
// pairs packed: src (16b, N<65536) | dst&255 (8b) << 16.
__global__ __launch_bounds__(THREADS)
void bucket_part(const int* __restrict__ src, const int* __restrict__ dst,
                 int* __restrict__ bucketFill, unsigned int* __restrict__ pairs,
                 int E, int NB) {
    __shared__ int lh[THREADS];
    __shared__ int lbase[THREADS];
    __shared__ int lo[THREADS];
    int chunk = (E + gridDim.x - 1) / gridDim.x;
    int e0 = blockIdx.x * chunk;
    int e1 = min(E, e0 + chunk);
    if (threadIdx.x < NB) { lh[threadIdx.x] = 0; lo[threadIdx.x] = 0; }
    __syncthreads();
    for (int e = e0 + threadIdx.x; e < e1; e += THREADS)
        atomicAdd(&lh[dst[e] >> 8], 1);
    __syncthreads();
    if (threadIdx.x < NB)
        lbase[threadIdx.x] = lh[threadIdx.x] ? atomicAdd(&bucketFill[threadIdx.x], lh[threadIdx.x]) : 0;
    __syncthreads();
    for (int e = e0 + threadIdx.x; e < e1; e += THREADS) {
        int d = dst[e];
        int bk = d >> 8;
        int pos = lbase[bk] + atomicAdd(&lo[bk], 1);
        pairs[pos] = (unsigned int)src[e] | ((unsigned int)(d & 255) << 16);
    }
}

// Level-2: one block per bucket. LDS degree hist + scan -> rowptr (coalesced),
// then scatter src ids (ushort) into exclusive csr region.
__global__ __launch_bounds__(THREADS)
void bucket_sort(const unsigned int* __restrict__ pairs, const int* __restrict__ bucket_base,
                 int* __restrict__ rowptr, unsigned short* __restrict__ csr_src, int N) {
    __shared__ int lhist[THREADS];
    __shared__ int lscan[THREADS];
    __shared__ int loff[THREADS];
    int b = blockIdx.x;
    int s0 = bucket_base[b], s1 = bucket_base[b + 1];
    lhist[threadIdx.x] = 0;
    __syncthreads();
    for (int i = s0 + threadIdx.x; i < s1; i += THREADS)
        atomicAdd(&lhist[(pairs[i] >> 16) & 255], 1);
    __syncthreads();
    int v = lhist[threadIdx.x];
    lscan[threadIdx.x] = v;
    __syncthreads();
    for (int off = 1; off < THREADS; off <<= 1) {
        int t = (threadIdx.x >= off) ? lscan[threadIdx.x - off] : 0;
        __syncthreads();
        lscan[threadIdx.x] += t;
        __syncthreads();
    }
    int base = s0 + lscan[threadIdx.x] - v;
    int id = (b << 8) + threadIdx.x;
    if (id < N) rowptr[id] = base;
    loff[threadIdx.x] = base;
    __syncthreads();
    for (int i = s0 + threadIdx.x; i < s1; i += THREADS) {
        unsigned int pr = pairs[i];
        int pos = atomicAdd(&loff[(pr >> 16) & 255], 1);
        csr_src[pos] = (unsigned short)(pr & 0xffffu);
    }
}

// ---------------------------------------------------------------------------
// MFMA bf16 GEMM: out[m][c] = A[m,:]@W[c,:] (+bias). M rows, K=128, NOUT cols.
// One wave per 16-row M-tile; B fragments (all NOUT/16 coltiles x 4 ksteps)
// VGPR-resident, loaded from pre-cast bf16 weights.
// Frag layouts (gfx950 16x16x32): A/B: [m|n=lane&15][k=quad*8+j];
// C/D: col=lane&15, row=quad*4+reg.
template<int NOUT, bool A32, bool OBF>
__global__ __launch_bounds__(THREADS)
void gemm_mfma(const void* __restrict__ Ap, const unsigned short* __restrict__ Wb,
               const float* __restrict__ bias, void* __restrict__ outp, int M) {
    constexpr int CT = NOUT / 16;
    const int wv = threadIdx.x >> 6, ln = threadIdx.x & 63;
    const int bl = ln & 15, quad = ln >> 4;
    const int mt = blockIdx.x * 4 + wv;

    ABfrag Bf[CT][4];
    #pragma unroll
    for (int ct = 0; ct < CT; ++ct)
        #pragma unroll
        for (int ks = 0; ks < 4; ++ks)
            Bf[ct][ks].q = *(const uint4*)&Wb[(size_t)(ct * 16 + bl) * 128 + ks * 32 + quad * 8];

    if (mt * 16 >= M) return;          // M divisible by 16 in this problem
    const int m0 = mt * 16;
    const int arow = m0 + bl;

    floatx4 acc[CT];
    #pragma unroll
    for (int ct = 0; ct < CT; ++ct) acc[ct] = (floatx4){0.f, 0.f, 0.f, 0.f};

    #pragma unroll
    for (int ks = 0; ks < 4; ++ks) {
        ABfrag Af;
        if (A32) {
            const float* A = (const float*)Ap;
            const float4* p4 = (const float4*)&A[(size_t)arow * 128 + ks * 32 + quad * 8];
            float4 u0 = p4[0], u1 = p4[1];
            Af.u[0] = f2bf(u0.x); Af.u[1] = f2bf(u0.y);
            Af.u[2] = f2bf(u0.z); Af.u[3] = f2bf(u0.w);
            Af.u[4] = f2bf(u1.x); Af.u[5] = f2bf(u1.y);
            Af.u[6] = f2bf(u1.z); Af.u[7] = f2bf(u1.w);
        } else {
            Af.q = *(const uint4*)&((const unsigned short*)Ap)[(size_t)arow * 128 + ks * 32 + quad * 8];
        }
        #pragma unroll
        for (int ct = 0; ct < CT; ++ct)
            acc[ct] = __builtin_amdgcn_mfma_f32_16x16x32_bf16(Af.v, Bf[ct][ks].v, acc[ct], 0, 0, 0);
    }

    #pragma unroll
    for (int ct = 0; ct < CT; ++ct) {
        int col = ct * 16 + bl;
        float bv = bias ? bias[col] : 0.f;
        #pragma unroll
        for (int i = 0; i < 4; ++i) {
            int row = m0 + quad * 4 + i;
            float v = acc[ct][i] + bv;
            if (OBF) ((unsigned short*)outp)[(size_t)row * NOUT + col] = f2bf(v);
            else     ((float*)outp)[(size_t)row * NOUT + col] = v;
        }
    }
}

// ---------------------------------------------------------------------------
// Gather-reduce layer 1: h[g][:] = relu( mean_{s in nbr(g)} p1[s][:] + r1[g][:] )
// bf16 table, fp32 accumulate, bf16 output. 16 lanes/node, 8 elems/lane.
__global__ __launch_bounds__(THREADS)
void gather_h(const unsigned short* __restrict__ p1, const int* __restrict__ rowptr,
              const unsigned short* __restrict__ csr, const float* __restrict__ r1,
              unsigned short* __restrict__ h, int N) {
    int g = blockIdx.x * 16 + (threadIdx.x >> 4);
    if (g >= N) return;
    int lane = threadIdx.x & 15;
    int start = rowptr[g], end = rowptr[g + 1];
    float acc[8] = {0.f, 0.f, 0.f, 0.f, 0.f, 0.f, 0.f, 0.f};
    int base = start;
    for (; base + 16 <= end; base += 16) {
        int sv = (int)csr[base + lane];
        #pragma unroll
        for (int j = 0; j < 16; ++j) {
            int s = __shfl(sv, j, 16);
            uint4 v = *(const uint4*)&p1[(size_t)s * 128 + lane * 8];
            acc[0] += __uint_as_float(v.x << 16);
            acc[1] += __uint_as_float(v.x & 0xffff0000u);
            acc[2] += __uint_as_float(v.y << 16);
            acc[3] += __uint_as_float(v.y & 0xffff0000u);
            acc[4] += __uint_as_float(v.z << 16);
            acc[5] += __uint_as_float(v.z & 0xffff0000u);
            acc[6] += __uint_as_float(v.w << 16);
            acc[7] += __uint_as_float(v.w & 0xffff0000u);
        }
    }
    if (base < end) {
        int my = base + lane;
        int sv = (my < end) ? (int)csr[my] : 0;
        int m = end - base;
        for (int j = 0; j < m; ++j) {
            int s = __shfl(sv, j, 16);
            uint4 v = *(const uint4*)&p1[(size_t)s * 128 + lane * 8];
            acc[0] += __uint_as_float(v.x << 16);
            acc[1] += __uint_as_float(v.x & 0xffff0000u);
            acc[2] += __uint_as_float(v.y << 16);
            acc[3] += __uint_as_float(v.y & 0xffff0000u);
            acc[4] += __uint_as_float(v.z << 16);
            acc[5] += __uint_as_float(v.z & 0xffff0000u);
            acc[6] += __uint_as_float(v.w << 16);
            acc[7] += __uint_as_float(v.w & 0xffff0000u);
        }
    }
    float rc = 1.0f / fmaxf((float)(end - start), 1.0f);
    const float4* r4 = (const float4*)&r1[(size_t)g * 128 + lane * 8];
    float4 a = r4[0], b = r4[1];
    float o[8];
    o[0] = fmaxf(acc[0] * rc + a.x, 0.f); o[1] = fmaxf(acc[1] * rc + a.y, 0.f);
    o[2] = fmaxf(acc[2] * rc + a.z, 0.f); o[3] = fmaxf(acc[3] * rc + a.w, 0.f);
    o[4] = fmaxf(acc[4] * rc + b.x, 0.f); o[5] = fmaxf(acc[5] * rc + b.y, 0.f);
    o[6] = fmaxf(acc[6] * rc + b.z, 0.f); o[7] = fmaxf(acc[7] * rc + b.w, 0.f);
    uint4 u;
    u.x = (unsigned)f2bf(o[0]) | ((unsigned)f2bf(o[1]) << 16);
    u.y = (unsigned)f2bf(o[2]) | ((unsigned)f2bf(o[3]) << 16);
    u.z = (unsigned)f2bf(o[4]) | ((unsigned)f2bf(o[5]) << 16);
    u.w = (unsigned)f2bf(o[6]) | ((unsigned)f2bf(o[7]) << 16);
    *(uint4*)&h[(size_t)g * 128 + lane * 8] = u;
}

// Gather-reduce layer 2 (final): out[g][:] = mean p2[nbr] + r2[g][:], fp32 out.
// 8 lanes/node, 8 elems/lane.
__global__ __launch_bounds__(THREADS)
void gather_out(const unsigned short* __restrict__ p2, const int* __restrict__ rowptr,
                const unsigned short* __restrict__ csr, const float* __restrict__ r2,
                float* __restrict__ out, int N) {
    int g = blockIdx.x * 32 + (threadIdx.x >> 3);
    if (g >= N) return;
    int lane = threadIdx.x & 7;
    int start = rowptr[g], end = rowptr[g + 1];
    float acc[8] = {0.f, 0.f, 0.f, 0.f, 0.f, 0.f, 0.f, 0.f};
    int base = start;
    for (; base + 8 <= end; base += 8) {
        int sv = (int)csr[base + lane];
        #pragma unroll
        for (int j = 0; j < 8; ++j) {
            int s = __shfl(sv, j, 8);
            uint4 v = *(const uint4*)&p2[(size_t)s * 64 + lane * 8];
            acc[0] += __uint_as_float(v.x << 16);
            acc[1] += __uint_as_float(v.x & 0xffff0000u);
            acc[2] += __uint_as_float(v.y << 16);
            acc[3] += __uint_as_float(v.y & 0xffff0000u);
            acc[4] += __uint_as_float(v.z << 16);
            acc[5] += __uint_as_float(v.z & 0xffff0000u);
            acc[6] += __uint_as_float(v.w << 16);
            acc[7] += __uint_as_float(v.w & 0xffff0000u);
        }
    }
    if (base < end) {
        int my = base + lane;
        int sv = (my < end) ? (int)csr[my] : 0;
        int m = end - base;
        for (int j = 0; j < m; ++j) {
            int s = __shfl(sv, j, 8);
            uint4 v = *(const uint4*)&p2[(size_t)s * 64 + lane * 8];
            acc[0] += __uint_as_float(v.x << 16);
            acc[1] += __uint_as_float(v.x & 0xffff0000u);
            acc[2] += __uint_as_float(v.y << 16);
            acc[3] += __uint_as_float(v.y & 0xffff0000u);
            acc[4] += __uint_as_float(v.z << 16);
            acc[5] += __uint_as_float(v.z & 0xffff0000u);
            acc[6] += __uint_as_float(v.w << 16);
            acc[7] += __uint_as_float(v.w & 0xffff0000u);
        }
    }
    float rc = 1.0f / fmaxf((float)(end - start), 1.0f);
    const float4* r4 = (const float4*)&r2[(size_t)g * 64 + lane * 8];
    float4 a = r4[0], b = r4[1];
    float4 o0 = make_float4(acc[0] * rc + a.x, acc[1] * rc + a.y,
                            acc[2] * rc + a.z, acc[3] * rc + a.w);
    float4 o1 = make_float4(acc[4] * rc + b.x, acc[5] * rc + b.y,
                            acc[6] * rc + b.z, acc[7] * rc + b.w);
    float4* o4 = (float4*)&out[(size_t)g * 64 + lane * 8];
    o4[0] = o0; o4[1] = o1;
}

// ---------------------------------------------------------------------------
extern "C" void kernel_launch(void* const* d_in, const int* in_sizes, int n_in,
                              void* d_out, int out_size, void* d_ws, size_t ws_size,
                              hipStream_t stream) {
    const float* x   = (const float*)d_in[0];
    const int* edges = (const int*)d_in[1];
    const float* Wl1 = (const float*)d_in[2];
    const float* Wr1 = (const float*)d_in[3];
    const float* b1  = (const float*)d_in[4];
    const float* Wl2 = (const float*)d_in[5];
    const float* Wr2 = (const float*)d_in[6];
    const float* b2  = (const float*)d_in[7];
    float* out = (float*)d_out;

    const int N = in_sizes[0] / 128;     // 50000 (< 65536: ushort packing valid)
    const int E = in_sizes[1] / 2;       // 1600000
    const int NB = (N + 255) >> 8;       // 196 coarse buckets
    const int* src = edges;
    const int* dstv = edges + E;

    // Workspace layout (16B-aligned segments)
    char* wsp = (char*)d_ws;
    unsigned short* p1  = (unsigned short*)wsp;  wsp += (size_t)N * 128 * 2;   // 12.8 MB
    float* r1           = (float*)wsp;           wsp += (size_t)N * 128 * 4;   // 25.6 MB
    unsigned short* h   = (unsigned short*)wsp;  wsp += (size_t)N * 128 * 2;   // 12.8 MB
    unsigned short* p2  = (unsigned short*)wsp;  wsp += (size_t)N * 64 * 2;    //  6.4 MB
    float* r2           = (float*)wsp;           wsp += (size_t)N * 64 * 4;    // 12.8 MB
    unsigned int* pairs = (unsigned int*)wsp;    wsp += (size_t)E * 4;         //  6.4 MB
    unsigned short* csr = (unsigned short*)wsp;  wsp += (size_t)E * 2;         //  3.2 MB
    unsigned short* Wb  = (unsigned short*)wsp;  wsp += (size_t)49152 * 2;     // 96 KB
    int* rowptr         = (int*)wsp;             wsp += (size_t)(N + 1) * 4;
    int* bhist          = (int*)wsp;             wsp += (size_t)NB * 4;
    int* bucket_base    = (int*)wsp;             wsp += (size_t)(NB + 1) * 4;
    int* bucketFill     = (int*)wsp;             wsp += (size_t)NB * 4;

    unsigned short* Wl1b = Wb;
    unsigned short* Wr1b = Wb + 16384;
    unsigned short* Wl2b = Wb + 32768;
    unsigned short* Wr2b = Wb + 40960;

    hipMemsetAsync(bhist, 0, (size_t)NB * sizeof(int), stream);

    // --- weight cast + CSR build ---
    cast_w<<<192, THREADS, 0, stream>>>(Wl1, Wr1, Wl2, Wr2, Wb);
    bucket_hist<<<400, THREADS, 0, stream>>>(dstv, bhist, E, NB);
    bucket_scan<<<1, THREADS, 0, stream>>>(bhist, bucket_base, bucketFill, rowptr, NB, N, E);
    bucket_part<<<512, THREADS, 0, stream>>>(src, dstv, bucketFill, pairs, E, NB);
    bucket_sort<<<NB, THREADS, 0, stream>>>(pairs, bucket_base, rowptr, csr, N);

    const int MT = (N + 15) / 16;                 // 3125 M-tiles
    const int gemmBlocks = (MT + 3) / 4;          // 4 waves (tiles) per block

    // --- layer 1 ---
    gemm_mfma<128, true, true ><<<gemmBlocks, THREADS, 0, stream>>>(x, Wl1b, nullptr, p1, N);
    gemm_mfma<128, true, false><<<gemmBlocks, THREADS, 0, stream>>>(x, Wr1b, b1, r1, N);
    gather_h<<<(N + 15) / 16, THREADS, 0, stream>>>(p1, rowptr, csr, r1, h, N);

    // --- layer 2 ---
    gemm_mfma<64, false, true ><<<gemmBlocks, THREADS, 0, stream>>>(h, Wl2b, nullptr, p2, N);
    gemm_mfma<64, false, false><<<gemmBlocks, THREADS, 0, stream>>>(h, Wr2b, b2, r2, N);
    gather_out<<<(N + 31) / 32, THREADS, 0, stream>>>(p2, rowptr, csr, r2, out, N);
}